// Round 4
// baseline (766.623 us; speedup 1.0000x reference)
//
#include <hip/hip_runtime.h>
#include <stdint.h>

typedef unsigned short u16;
typedef __attribute__((ext_vector_type(8))) short s16x8;
typedef __attribute__((ext_vector_type(8))) unsigned short u16x8;
typedef __attribute__((ext_vector_type(4))) float f32x4;

#define N_TOK 8192
#define DDIM 2048
#define HDIM 2048
#define NROWS 16384
#define PADROWS 16640
#define MAXTILES 72
#define KTILES 32

// ---- ws layout (bytes) ----
#define W1T_OFF    0ull
#define W3T_OFF    67108864ull
#define W2T_OFF    134217728ull
#define XBF_OFF    201326592ull
#define HS_OFF     234881024ull              // 16640 x 2048 bf16 = 68,157,440
#define ROWTOK_OFF 303038464ull              // 16640 ints (pad to 68608)
#define POS_OFF    303107072ull              // 16384 ints
#define META_OFF   303172608ull              // 32 ints
#define RES_OFF    0ull                      // overlays w1T/w3T (dead after gemm1)
#define WS_NEED    303172736ull

__device__ __forceinline__ u16 f2bf(float f) {
  union { float f; unsigned u; } v; v.f = f;
  unsigned r = v.u + 0x7fffu + ((v.u >> 16) & 1u);
  return (u16)(r >> 16);
}
__device__ __forceinline__ float bf2f(u16 u) {
  union { unsigned u; float f; } v; v.u = ((unsigned)u) << 16; return v.f;
}
__device__ __forceinline__ void gload_lds16(const u16* g, u16* l) {
  __builtin_amdgcn_global_load_lds(
      (const __attribute__((address_space(1))) unsigned int*)g,
      (__attribute__((address_space(3))) unsigned int*)l, 16, 0, 0);
}

// ---------------- routing ----------------
__global__ void r1_kernel(const int* __restrict__ bsz, int* __restrict__ meta,
                          int* __restrict__ rowtok) {
  if (threadIdx.x == 0) {
    int off = 0, tbv = 0;
    meta[8] = 0; meta[17] = 0;
    for (int e = 0; e < 8; ++e) {
      meta[e] = 0;                           // atomic counters
      int c = bsz[e];
      off += c;  meta[9 + e] = off;          // offs[e+1]
      tbv += (c + 255) >> 8; meta[18 + e] = tbv;  // tb256[e+1]
    }
  }
  for (int p = NROWS + (int)threadIdx.x; p < PADROWS; p += 256) rowtok[p] = 0;
}

__global__ void r2_kernel(const int* __restrict__ eidx, int* __restrict__ meta,
                          int* __restrict__ rowtok, int* __restrict__ posOf) {
  int i = blockIdx.x * 256 + threadIdx.x;  // < 16384
  int e = eidx[i];
  int p = atomicAdd(&meta[e], 1);
  int row = meta[8 + e] + p;
  rowtok[row] = i >> 1;
  posOf[i] = row;
}

// ---------------- converts ----------------
__global__ void convert_x_kernel(const float* __restrict__ x, u16* __restrict__ xbf) {
  long long c = blockIdx.x * 256 + threadIdx.x;
  const float4 v0 = *(const float4*)&x[c * 8];
  const float4 v1 = *(const float4*)&x[c * 8 + 4];
  u16x8 u;
  u[0] = f2bf(v0.x); u[1] = f2bf(v0.y); u[2] = f2bf(v0.z); u[3] = f2bf(v0.w);
  u[4] = f2bf(v1.x); u[5] = f2bf(v1.y); u[6] = f2bf(v1.z); u[7] = f2bf(v1.w);
  *(u16x8*)&xbf[c * 8] = u;
}

__global__ __launch_bounds__(256) void transpose_cvt_kernel(
    const float* __restrict__ w1, const float* __restrict__ w2, const float* __restrict__ w3,
    u16* __restrict__ w1T, u16* __restrict__ w2T, u16* __restrict__ w3T) {
  __shared__ float tile[64][65];
  int z = blockIdx.z;
  const float* src; u16* dst;
  if (z < 8)        { src = w1 + (size_t)z * 4194304;        dst = w1T + (size_t)z * 4194304; }
  else if (z < 16)  { src = w3 + (size_t)(z - 8) * 4194304;  dst = w3T + (size_t)(z - 8) * 4194304; }
  else              { src = w2 + (size_t)(z - 16) * 4194304; dst = w2T + (size_t)(z - 16) * 4194304; }
  int r0 = blockIdx.y * 64, c0 = blockIdx.x * 64;
  int tid = threadIdx.x;
  int lr = tid >> 4, lc4 = (tid & 15) * 4;
#pragma unroll
  for (int i = 0; i < 4; ++i) {
    const float4 v = *(const float4*)&src[(size_t)(r0 + lr + i * 16) * 2048 + c0 + lc4];
    tile[lr + i * 16][lc4 + 0] = v.x; tile[lr + i * 16][lc4 + 1] = v.y;
    tile[lr + i * 16][lc4 + 2] = v.z; tile[lr + i * 16][lc4 + 3] = v.w;
  }
  __syncthreads();
  int orb = tid >> 3, oc8 = (tid & 7) * 8;
#pragma unroll
  for (int i = 0; i < 2; ++i) {
    int orow = orb + i * 32;
    u16x8 u;
#pragma unroll
    for (int j = 0; j < 8; ++j) u[j] = f2bf(tile[oc8 + j][orow]);
    *(u16x8*)&dst[(size_t)(c0 + orow) * 2048 + r0 + oc8] = u;
  }
}

// ---------------- grouped dual-B GEMM, 4-phase m201-style schedule ----------------
// EPI=1: out[row][colb*128+c] = silu(A@B1) * (A@B3)   (B1=w1T,B3=w3T panels, 128 cols)
// EPI=0: out[row][colb*256+c] = A@B1 ; +128 cols = A@B3 (B1m=B3m=w2T, two sub-panels)
template<int EPI>
__device__ __forceinline__ void gemm_body(
    const u16* __restrict__ A, const u16* __restrict__ B1m, const u16* __restrict__ B3m,
    const int* __restrict__ gather, const int* __restrict__ meta, u16* __restrict__ out) {
  const int* offs = meta + 8;
  const int* tb = meta + 17;

  // bijective XCD chunking (m204)
  const int nwg = (int)(gridDim.x * gridDim.y);
  const int lin = (int)(blockIdx.y * gridDim.x + blockIdx.x);
  const int q8 = nwg >> 3, r8 = nwg & 7;
  const int xcd = lin & 7, idx = lin >> 3;
  const int nl = (xcd < r8 ? xcd * (q8 + 1) : r8 * (q8 + 1) + (xcd - r8) * q8) + idx;
  const int tileId = nl % MAXTILES;
  const int colb = nl / MAXTILES;

  if (tileId >= tb[8]) return;
  int e = 0;
#pragma unroll
  for (int qq = 1; qq < 8; ++qq) if (tileId >= tb[qq]) e = qq;
  const int row0 = offs[e] + (tileId - tb[e]) * 256;
  const int vr = offs[e + 1] - row0;

  const int bRowA = EPI ? colb * 128 : colb * 256;
  const int bRowB = EPI ? colb * 128 : colb * 256 + 128;

  __shared__ u16 lds[2][4][8192];  // [buf][A0,A1,B1,B3] = 128 KiB

  const int tid = threadIdx.x;
  const int wid = tid >> 6, lane = tid & 63;
  const int lm = lane & 15, kg = lane >> 4;
  const int wr = wid >> 2, wc = wid & 3;

  // ---- stage pointers (2 loads per unit per thread), chunk-permuted source
  const u16* pA0[2]; const u16* pA1[2]; const u16* pB1[2]; const u16* pB3[2];
#pragma unroll
  for (int l = 0; l < 2; ++l) {
    int S = (wid * 2 + l) * 64 + lane;
    int r = S >> 3;
    int c8 = ((S & 7) ^ (r & 7)) * 8;
    int ga0 = row0 + r, ga1 = row0 + 128 + r;
    int ta0 = gather ? gather[ga0] : ga0;
    int ta1 = gather ? gather[ga1] : ga1;
    pA0[l] = A + (size_t)ta0 * 2048 + c8;
    pA1[l] = A + (size_t)ta1 * 2048 + c8;
    pB1[l] = B1m + ((size_t)e * 2048 + bRowA + r) * 2048 + c8;
    pB3[l] = B3m + ((size_t)e * 2048 + bRowB + r) * 2048 + c8;
  }

  // frag-read offsets: elem = lm*64 + ((kk*4+kg)^(lm&7))*8
  int fA[2];
  fA[0] = lm * 64 + ((kg) ^ (lm & 7)) * 8;
  fA[1] = lm * 64 + ((4 + kg) ^ (lm & 7)) * 8;

  f32x4 acc1[8][2], acc3[8][2];
  f32x4 z4 = {0.f, 0.f, 0.f, 0.f};
#pragma unroll
  for (int m = 0; m < 8; ++m)
#pragma unroll
    for (int n = 0; n < 2; ++n) { acc1[m][n] = z4; acc3[m][n] = z4; }

#define STG(b, u, P) do { \
    gload_lds16(P[0], &lds[b][u][(wid * 2 + 0) * 512]); \
    gload_lds16(P[1], &lds[b][u][(wid * 2 + 1) * 512]); } while (0)
#define STG_ALL(b) do { STG(b, 0, pA0); STG(b, 1, pA1); \
    STG(b, 2, pB1); STG(b, 3, pB3); } while (0)
#define ADV() do { pA0[0]+=64; pA0[1]+=64; pA1[0]+=64; pA1[1]+=64; \
    pB1[0]+=64; pB1[1]+=64; pB3[0]+=64; pB3[1]+=64; } while (0)

  // prologue: stage tile 0 (8 loads/thread in flight)
  STG_ALL(0);
  ADV();

  s16x8 a[4][2], b1r[2][2], b3r[2][2];

#define READ_A(half) do { \
_Pragma("unroll") \
    for (int mi = 0; mi < 4; ++mi) \
_Pragma("unroll") \
      for (int kk = 0; kk < 2; ++kk) \
        a[mi][kk] = *(const s16x8*)&lds[cur][wr][((half) * 4 + mi) * 1024 + fA[kk]]; \
    } while (0)
#define READ_B1() do { \
_Pragma("unroll") \
    for (int n = 0; n < 2; ++n) \
_Pragma("unroll") \
      for (int kk = 0; kk < 2; ++kk) \
        b1r[n][kk] = *(const s16x8*)&lds[cur][2][wc * 2048 + n * 1024 + fA[kk]]; \
    } while (0)
#define READ_B3() do { \
_Pragma("unroll") \
    for (int n = 0; n < 2; ++n) \
_Pragma("unroll") \
      for (int kk = 0; kk < 2; ++kk) \
        b3r[n][kk] = *(const s16x8*)&lds[cur][3][wc * 2048 + n * 1024 + fA[kk]]; \
    } while (0)
#define MFMA16(ACC, half, B) do { \
    __builtin_amdgcn_s_setprio(1); \
_Pragma("unroll") \
    for (int mi = 0; mi < 4; ++mi) \
_Pragma("unroll") \
      for (int n = 0; n < 2; ++n) { \
        ACC[(half)*4+mi][n] = __builtin_amdgcn_mfma_f32_16x16x32_bf16(a[mi][0], B[n][0], ACC[(half)*4+mi][n], 0, 0, 0); \
        ACC[(half)*4+mi][n] = __builtin_amdgcn_mfma_f32_16x16x32_bf16(a[mi][1], B[n][1], ACC[(half)*4+mi][n], 0, 0, 0); \
      } \
    __builtin_amdgcn_s_setprio(0); } while (0)
#define LGKM0() asm volatile("s_waitcnt lgkmcnt(0)" ::: "memory")

  for (int t = 0; t < KTILES; ++t) {
    const int cur = t & 1;
    // tile entry: stage t+1 into buf^1 (free: previous end-of-tile barrier),
    // counted wait for tile t's 8 loads (issued one full tile ago)
    if (t + 1 < KTILES) {
      STG_ALL(cur ^ 1);
      ADV();
      asm volatile("s_waitcnt vmcnt(8)" ::: "memory");
    } else {
      asm volatile("s_waitcnt vmcnt(0)" ::: "memory");
    }
    __builtin_amdgcn_s_barrier();   // buf[cur] certified staged for all waves

    // ---- phase 0: A-half0 (8 reads) + B1 (4 reads) -> acc1 half0
    READ_A(0);
    READ_B1();
    asm volatile("s_waitcnt lgkmcnt(8)" ::: "memory");
    __builtin_amdgcn_s_barrier();
    LGKM0();
    MFMA16(acc1, 0, b1r);
    __builtin_amdgcn_s_barrier();

    // ---- phase 1: B3 (4 reads) -> acc3 half0 (a regs reused)
    READ_B3();
    __builtin_amdgcn_s_barrier();
    LGKM0();
    MFMA16(acc3, 0, b3r);
    __builtin_amdgcn_s_barrier();

    // ---- phase 2: A-half1 (8 reads) -> acc1 half1 (b1r reused)
    READ_A(1);
    __builtin_amdgcn_s_barrier();
    LGKM0();
    MFMA16(acc1, 1, b1r);
    __builtin_amdgcn_s_barrier();

    // ---- phase 3: no reads -> acc3 half1 (a, b3r reused)
    MFMA16(acc3, 1, b3r);
    __builtin_amdgcn_s_barrier();   // end-of-tile: all readers of buf[cur] done
  }

  // ---- epilogue
#pragma unroll
  for (int m = 0; m < 8; ++m)
#pragma unroll
    for (int n = 0; n < 2; ++n) {
      const int rloc = wr * 128 + m * 16 + kg * 4;
      if (EPI == 1) {
        const int col = colb * 128 + wc * 32 + n * 16 + lm;
#pragma unroll
        for (int rr = 0; rr < 4; ++rr) {
          int rowl = rloc + rr;
          if (rowl < vr) {
            float z = acc1[m][n][rr];
            float h = z / (1.f + __expf(-z)) * acc3[m][n][rr];
            out[(size_t)(row0 + rowl) * 2048 + col] = f2bf(h);
          }
        }
      } else {
        const int col = colb * 256 + wc * 32 + n * 16 + lm;
#pragma unroll
        for (int rr = 0; rr < 4; ++rr) {
          int rowl = rloc + rr;
          if (rowl < vr) {
            out[(size_t)(row0 + rowl) * 2048 + col] = f2bf(acc1[m][n][rr]);
            out[(size_t)(row0 + rowl) * 2048 + col + 128] = f2bf(acc3[m][n][rr]);
          }
        }
      }
    }
#undef STG
#undef STG_ALL
#undef ADV
#undef READ_A
#undef READ_B1
#undef READ_B3
#undef MFMA16
#undef LGKM0
}

__global__ __launch_bounds__(512, 2) void gemm1_kernel(
    const u16* __restrict__ A, const u16* __restrict__ B1m, const u16* __restrict__ B3m,
    const int* __restrict__ gather, const int* __restrict__ meta, u16* __restrict__ out) {
  gemm_body<1>(A, B1m, B3m, gather, meta, out);
}
__global__ __launch_bounds__(512, 2) void gemm2_kernel(
    const u16* __restrict__ A, const u16* __restrict__ B1m, const u16* __restrict__ B3m,
    const int* __restrict__ gather, const int* __restrict__ meta, u16* __restrict__ out) {
  gemm_body<0>(A, B1m, B3m, gather, meta, out);
}

// ---------------- combine ----------------
__global__ void combine_kernel(const u16* __restrict__ res, const int* __restrict__ posOf,
                               const float* __restrict__ ew, float* __restrict__ out) {
  int c = blockIdx.x * 256 + threadIdx.x;
  int t = c >> 8, dc = (c & 255) * 8;
  int p0 = posOf[2 * t], p1 = posOf[2 * t + 1];
  float wa = ew[2 * t], wb = ew[2 * t + 1];
  u16x8 u0 = *(const u16x8*)&res[(size_t)p0 * 2048 + dc];
  u16x8 u1 = *(const u16x8*)&res[(size_t)p1 * 2048 + dc];
  float4 o0, o1;
  o0.x = wa * bf2f(u0[0]) + wb * bf2f(u1[0]);
  o0.y = wa * bf2f(u0[1]) + wb * bf2f(u1[1]);
  o0.z = wa * bf2f(u0[2]) + wb * bf2f(u1[2]);
  o0.w = wa * bf2f(u0[3]) + wb * bf2f(u1[3]);
  o1.x = wa * bf2f(u0[4]) + wb * bf2f(u1[4]);
  o1.y = wa * bf2f(u0[5]) + wb * bf2f(u1[5]);
  o1.z = wa * bf2f(u0[6]) + wb * bf2f(u1[6]);
  o1.w = wa * bf2f(u0[7]) + wb * bf2f(u1[7]);
  *(float4*)&out[(size_t)t * 2048 + dc] = o0;
  *(float4*)&out[(size_t)t * 2048 + dc + 4] = o1;
}

extern "C" void kernel_launch(void* const* d_in, const int* in_sizes, int n_in,
                              void* d_out, int out_size, void* d_ws, size_t ws_size,
                              hipStream_t stream) {
  const float* x  = (const float*)d_in[0];
  const float* ew = (const float*)d_in[1];
  const int* eidx = (const int*)d_in[2];
  const int* bsz  = (const int*)d_in[3];
  const float* w1 = (const float*)d_in[4];
  const float* w2 = (const float*)d_in[5];
  const float* w3 = (const float*)d_in[6];
  float* out = (float*)d_out;
  char* ws = (char*)d_ws;

  if (ws_size < WS_NEED) {
    hipMemsetAsync(d_out, 0, (size_t)out_size * 4, stream);
    return;
  }

  u16* w1T = (u16*)(ws + W1T_OFF);
  u16* w3T = (u16*)(ws + W3T_OFF);
  u16* w2T = (u16*)(ws + W2T_OFF);
  u16* xbf = (u16*)(ws + XBF_OFF);
  u16* hs  = (u16*)(ws + HS_OFF);
  u16* res = (u16*)(ws + RES_OFF);   // overlays w1T/w3T (dead after gemm1)
  int* rowtok = (int*)(ws + ROWTOK_OFF);
  int* posOf  = (int*)(ws + POS_OFF);
  int* meta   = (int*)(ws + META_OFF);

  r1_kernel<<<1, 256, 0, stream>>>(bsz, meta, rowtok);
  r2_kernel<<<64, 256, 0, stream>>>(eidx, meta, rowtok, posOf);
  convert_x_kernel<<<8192, 256, 0, stream>>>(x, xbf);
  transpose_cvt_kernel<<<dim3(32, 32, 24), 256, 0, stream>>>(w1, w2, w3, w1T, w2T, w3T);
  gemm1_kernel<<<dim3(MAXTILES, 16), 512, 0, stream>>>(xbf, w1T, w3T, rowtok, meta, hs);
  gemm2_kernel<<<dim3(MAXTILES, 8), 512, 0, stream>>>(hs, w2T, w2T, nullptr, meta, res);
  combine_kernel<<<8192, 256, 0, stream>>>(res, posOf, ew, out);
}

// Round 8
// 708.818 us; speedup vs baseline: 1.0816x; 1.0816x over previous
//
#include <hip/hip_runtime.h>
#include <stdint.h>

typedef unsigned short u16;
typedef __attribute__((ext_vector_type(8))) short s16x8;
typedef __attribute__((ext_vector_type(8))) unsigned short u16x8;
typedef __attribute__((ext_vector_type(4))) float f32x4;

#define N_TOK 8192
#define DDIM 2048
#define HDIM 2048
#define NROWS 16384
#define PADROWS 16640
#define MAXTILES 72
#define KTILES 32

// ---- ws layout (bytes) ----
#define W1T_OFF    0ull
#define W3T_OFF    67108864ull
#define W2T_OFF    134217728ull
#define XBF_OFF    201326592ull
#define HS_OFF     234881024ull              // 16640 x 2048 bf16
#define ROWTOK_OFF 303038464ull
#define POS_OFF    303107072ull
#define META_OFF   303172608ull
#define RES_OFF    0ull                      // overlays w1T/w3T (dead after gemm1)
#define WS_NEED    303172736ull

__device__ __forceinline__ u16 f2bf(float f) {
  union { float f; unsigned u; } v; v.f = f;
  unsigned r = v.u + 0x7fffu + ((v.u >> 16) & 1u);
  return (u16)(r >> 16);
}
__device__ __forceinline__ float bf2f(u16 u) {
  union { unsigned u; float f; } v; v.u = ((unsigned)u) << 16; return v.f;
}
__device__ __forceinline__ void gload_lds16(const u16* g, u16* l) {
  __builtin_amdgcn_global_load_lds(
      (const __attribute__((address_space(1))) unsigned int*)g,
      (__attribute__((address_space(3))) unsigned int*)l, 16, 0, 0);
}

// ---------------- routing ----------------
__global__ void r1_kernel(const int* __restrict__ bsz, int* __restrict__ meta,
                          int* __restrict__ rowtok) {
  if (threadIdx.x == 0) {
    int off = 0, tbv = 0;
    meta[8] = 0; meta[17] = 0;
    for (int e = 0; e < 8; ++e) {
      meta[e] = 0;                           // atomic counters
      int c = bsz[e];
      off += c;  meta[9 + e] = off;          // offs[e+1]
      tbv += (c + 255) >> 8; meta[18 + e] = tbv;  // tb256[e+1]
    }
  }
  for (int p = NROWS + (int)threadIdx.x; p < PADROWS; p += 256) rowtok[p] = 0;
}

__global__ void r2_kernel(const int* __restrict__ eidx, int* __restrict__ meta,
                          int* __restrict__ rowtok, int* __restrict__ posOf) {
  int i = blockIdx.x * 256 + threadIdx.x;
  int e = eidx[i];
  int p = atomicAdd(&meta[e], 1);
  int row = meta[8 + e] + p;
  rowtok[row] = i >> 1;
  posOf[i] = row;
}

// ---------------- converts ----------------
__global__ void convert_x_kernel(const float* __restrict__ x, u16* __restrict__ xbf) {
  long long c = blockIdx.x * 256 + threadIdx.x;
  const float4 v0 = *(const float4*)&x[c * 8];
  const float4 v1 = *(const float4*)&x[c * 8 + 4];
  u16x8 u;
  u[0] = f2bf(v0.x); u[1] = f2bf(v0.y); u[2] = f2bf(v0.z); u[3] = f2bf(v0.w);
  u[4] = f2bf(v1.x); u[5] = f2bf(v1.y); u[6] = f2bf(v1.z); u[7] = f2bf(v1.w);
  *(u16x8*)&xbf[c * 8] = u;
}

__global__ __launch_bounds__(256) void transpose_cvt_kernel(
    const float* __restrict__ w1, const float* __restrict__ w2, const float* __restrict__ w3,
    u16* __restrict__ w1T, u16* __restrict__ w2T, u16* __restrict__ w3T) {
  __shared__ float tile[64][65];
  int z = blockIdx.z;
  const float* src; u16* dst;
  if (z < 8)        { src = w1 + (size_t)z * 4194304;        dst = w1T + (size_t)z * 4194304; }
  else if (z < 16)  { src = w3 + (size_t)(z - 8) * 4194304;  dst = w3T + (size_t)(z - 8) * 4194304; }
  else              { src = w2 + (size_t)(z - 16) * 4194304; dst = w2T + (size_t)(z - 16) * 4194304; }
  int r0 = blockIdx.y * 64, c0 = blockIdx.x * 64;
  int tid = threadIdx.x;
  int lr = tid >> 4, lc4 = (tid & 15) * 4;
#pragma unroll
  for (int i = 0; i < 4; ++i) {
    const float4 v = *(const float4*)&src[(size_t)(r0 + lr + i * 16) * 2048 + c0 + lc4];
    tile[lr + i * 16][lc4 + 0] = v.x; tile[lr + i * 16][lc4 + 1] = v.y;
    tile[lr + i * 16][lc4 + 2] = v.z; tile[lr + i * 16][lc4 + 3] = v.w;
  }
  __syncthreads();
  int orb = tid >> 3, oc8 = (tid & 7) * 8;
#pragma unroll
  for (int i = 0; i < 2; ++i) {
    int orow = orb + i * 32;
    u16x8 u;
#pragma unroll
    for (int j = 0; j < 8; ++j) u[j] = f2bf(tile[oc8 + j][orow]);
    *(u16x8*)&dst[(size_t)(c0 + orow) * 2048 + r0 + oc8] = u;
  }
}

// ---------------- grouped dual-B GEMM (R3-proven schedule + super-block mapping) ----------------
// EPI=1: out[row][colb*128+c] = silu(A@B1) * (A@B3)
// EPI=0: out[row][colb*256+c] = A@B1 ; +128 = A@B3 (both = w2T sub-panels)
template<int EPI>
__device__ __forceinline__ void gemm_body(
    const u16* __restrict__ A, const u16* __restrict__ B1m, const u16* __restrict__ B3m,
    const int* __restrict__ gather, const int* __restrict__ meta, u16* __restrict__ out) {
  const int* offs = meta + 8;
  const int* tb = meta + 17;

  // --- XCD super-block locality mapping ---
  // HW round-robins blockIdx over 8 XCDs (xcd = blockIdx & 7). Per XCD we walk
  // super-blocks of 8 tileIds x 4 colbs = 32 works (= 32 CUs, all co-resident):
  // the 4-colb B-group (~4 MB) lives in that XCD's L2 and is reused by 8 row
  // tiles; consecutive super-blocks share the tileId-group so A stays hot.
  const int NCOLB = EPI ? 16 : 8;
  const int CG = NCOLB / 4;                 // colb-groups of 4
  const int nper = (MAXTILES * NCOLB) / 8;  // works per XCD (144 / 72)
  const int lin = (int)blockIdx.x;
  const int w = (lin & 7) * nper + (lin >> 3);
  const int sb = w >> 5, t5 = w & 31;
  const int tileId = (sb / CG) * 8 + (t5 >> 2);
  const int colb = (sb % CG) * 4 + (t5 & 3);

  if (tileId >= tb[8]) return;
  int e = 0;
#pragma unroll
  for (int qq = 1; qq < 8; ++qq) if (tileId >= tb[qq]) e = qq;
  const int row0 = offs[e] + (tileId - tb[e]) * 256;
  const int vr = offs[e + 1] - row0;

  const int bRowA = EPI ? colb * 128 : colb * 256;
  const int bRowB = EPI ? colb * 128 : colb * 256 + 128;

  __shared__ u16 lds[2][4][8192];  // [buf][A0,A1,B1,B3] = 128 KiB

  const int tid = threadIdx.x;
  const int wid = tid >> 6, lane = tid & 63;
  const int lm = lane & 15, kg = lane >> 4;
  const int wr = wid >> 2, wc = wid & 3;

  // stage pointers (2 loads per unit per thread), chunk-permuted source
  const u16* pA0[2]; const u16* pA1[2]; const u16* pB1[2]; const u16* pB3[2];
#pragma unroll
  for (int l = 0; l < 2; ++l) {
    int S = (wid * 2 + l) * 64 + lane;
    int r = S >> 3;
    int c8 = ((S & 7) ^ (r & 7)) * 8;
    int ga0 = row0 + r, ga1 = row0 + 128 + r;
    int ta0 = gather ? gather[ga0] : ga0;
    int ta1 = gather ? gather[ga1] : ga1;
    pA0[l] = A + (size_t)ta0 * 2048 + c8;
    pA1[l] = A + (size_t)ta1 * 2048 + c8;
    pB1[l] = B1m + ((size_t)e * 2048 + bRowA + r) * 2048 + c8;
    pB3[l] = B3m + ((size_t)e * 2048 + bRowB + r) * 2048 + c8;
  }

  // frag-read offsets: elem = lm*64 + ((kk*4+kg)^(lm&7))*8
  int fA[2];
  fA[0] = lm * 64 + ((kg) ^ (lm & 7)) * 8;
  fA[1] = lm * 64 + ((4 + kg) ^ (lm & 7)) * 8;

  f32x4 acc1[8][2], acc3[8][2];
  f32x4 z4 = {0.f, 0.f, 0.f, 0.f};
#pragma unroll
  for (int m = 0; m < 8; ++m)
#pragma unroll
    for (int n = 0; n < 2; ++n) { acc1[m][n] = z4; acc3[m][n] = z4; }

#define STG(b, u, P) do { \
    gload_lds16(P[0], &lds[b][u][(wid * 2 + 0) * 512]); \
    gload_lds16(P[1], &lds[b][u][(wid * 2 + 1) * 512]); } while (0)
#define STG_ALL(b) do { STG(b, 0, pA0); STG(b, 1, pA1); \
    STG(b, 2, pB1); STG(b, 3, pB3); } while (0)
#define ADV() do { pA0[0]+=64; pA0[1]+=64; pA1[0]+=64; pA1[1]+=64; \
    pB1[0]+=64; pB1[1]+=64; pB3[0]+=64; pB3[1]+=64; } while (0)

  // prologue: stage tile 0 (8 loads/thread in flight)
  STG_ALL(0);
  ADV();

  s16x8 a[4][2], b1r[2][2], b3r[2][2];

#define READ_B() do { \
_Pragma("unroll") \
    for (int n = 0; n < 2; ++n) \
_Pragma("unroll") \
      for (int kk = 0; kk < 2; ++kk) { \
        b1r[n][kk] = *(const s16x8*)&lds[cur][2][wc * 2048 + n * 1024 + fA[kk]]; \
        b3r[n][kk] = *(const s16x8*)&lds[cur][3][wc * 2048 + n * 1024 + fA[kk]]; \
      } } while (0)
#define READ_A(half) do { \
_Pragma("unroll") \
    for (int mi = 0; mi < 4; ++mi) \
_Pragma("unroll") \
      for (int kk = 0; kk < 2; ++kk) \
        a[mi][kk] = *(const s16x8*)&lds[cur][wr][((half) * 4 + mi) * 1024 + fA[kk]]; \
    } while (0)
#define MFMA32(half) do { \
    __builtin_amdgcn_s_setprio(1); \
_Pragma("unroll") \
    for (int mi = 0; mi < 4; ++mi) \
_Pragma("unroll") \
      for (int n = 0; n < 2; ++n) { \
        acc1[(half)*4+mi][n] = __builtin_amdgcn_mfma_f32_16x16x32_bf16(a[mi][0], b1r[n][0], acc1[(half)*4+mi][n], 0, 0, 0); \
        acc1[(half)*4+mi][n] = __builtin_amdgcn_mfma_f32_16x16x32_bf16(a[mi][1], b1r[n][1], acc1[(half)*4+mi][n], 0, 0, 0); \
        acc3[(half)*4+mi][n] = __builtin_amdgcn_mfma_f32_16x16x32_bf16(a[mi][0], b3r[n][0], acc3[(half)*4+mi][n], 0, 0, 0); \
        acc3[(half)*4+mi][n] = __builtin_amdgcn_mfma_f32_16x16x32_bf16(a[mi][1], b3r[n][1], acc3[(half)*4+mi][n], 0, 0, 0); \
      } \
    __builtin_amdgcn_s_setprio(0); } while (0)

  // hot loop: tiles 0 .. KTILES-2, each stages tile t+1 and uses counted vmcnt(8)
  for (int t = 0; t < KTILES - 1; ++t) {
    const int cur = t & 1;
    STG_ALL(cur ^ 1);
    ADV();
    asm volatile("s_waitcnt vmcnt(8)" ::: "memory");   // tile t landed; t+1 in flight
    __builtin_amdgcn_s_barrier();
    READ_A(0);
    READ_B();
    MFMA32(0);
    __builtin_amdgcn_s_barrier();
    READ_A(1);
    MFMA32(1);
    __builtin_amdgcn_s_barrier();   // certifies all reads of buf[cur] done
  }
  // final tile
  {
    const int cur = (KTILES - 1) & 1;
    asm volatile("s_waitcnt vmcnt(0)" ::: "memory");
    __builtin_amdgcn_s_barrier();
    READ_A(0);
    READ_B();
    MFMA32(0);
    __builtin_amdgcn_s_barrier();
    READ_A(1);
    MFMA32(1);
  }

  // ---- epilogue
#pragma unroll
  for (int m = 0; m < 8; ++m)
#pragma unroll
    for (int n = 0; n < 2; ++n) {
      const int rloc = wr * 128 + m * 16 + kg * 4;
      if (EPI == 1) {
        const int col = colb * 128 + wc * 32 + n * 16 + lm;
#pragma unroll
        for (int rr = 0; rr < 4; ++rr) {
          int rowl = rloc + rr;
          if (rowl < vr) {
            float z = acc1[m][n][rr];
            float h = z / (1.f + __expf(-z)) * acc3[m][n][rr];
            out[(size_t)(row0 + rowl) * 2048 + col] = f2bf(h);
          }
        }
      } else {
        const int col = colb * 256 + wc * 32 + n * 16 + lm;
#pragma unroll
        for (int rr = 0; rr < 4; ++rr) {
          int rowl = rloc + rr;
          if (rowl < vr) {
            out[(size_t)(row0 + rowl) * 2048 + col] = f2bf(acc1[m][n][rr]);
            out[(size_t)(row0 + rowl) * 2048 + col + 128] = f2bf(acc3[m][n][rr]);
          }
        }
      }
    }
#undef STG
#undef STG_ALL
#undef ADV
#undef READ_B
#undef READ_A
#undef MFMA32
}

__global__ __launch_bounds__(512, 2) void gemm1_kernel(
    const u16* __restrict__ A, const u16* __restrict__ B1m, const u16* __restrict__ B3m,
    const int* __restrict__ gather, const int* __restrict__ meta, u16* __restrict__ out) {
  gemm_body<1>(A, B1m, B3m, gather, meta, out);
}
__global__ __launch_bounds__(512, 2) void gemm2_kernel(
    const u16* __restrict__ A, const u16* __restrict__ B1m, const u16* __restrict__ B3m,
    const int* __restrict__ gather, const int* __restrict__ meta, u16* __restrict__ out) {
  gemm_body<0>(A, B1m, B3m, gather, meta, out);
}

// ---------------- combine ----------------
__global__ void combine_kernel(const u16* __restrict__ res, const int* __restrict__ posOf,
                               const float* __restrict__ ew, float* __restrict__ out) {
  int c = blockIdx.x * 256 + threadIdx.x;
  int t = c >> 8, dc = (c & 255) * 8;
  int p0 = posOf[2 * t], p1 = posOf[2 * t + 1];
  float wa = ew[2 * t], wb = ew[2 * t + 1];
  u16x8 u0 = *(const u16x8*)&res[(size_t)p0 * 2048 + dc];
  u16x8 u1 = *(const u16x8*)&res[(size_t)p1 * 2048 + dc];
  float4 o0, o1;
  o0.x = wa * bf2f(u0[0]) + wb * bf2f(u1[0]);
  o0.y = wa * bf2f(u0[1]) + wb * bf2f(u1[1]);
  o0.z = wa * bf2f(u0[2]) + wb * bf2f(u1[2]);
  o0.w = wa * bf2f(u0[3]) + wb * bf2f(u1[3]);
  o1.x = wa * bf2f(u0[4]) + wb * bf2f(u1[4]);
  o1.y = wa * bf2f(u0[5]) + wb * bf2f(u1[5]);
  o1.z = wa * bf2f(u0[6]) + wb * bf2f(u1[6]);
  o1.w = wa * bf2f(u0[7]) + wb * bf2f(u1[7]);
  *(float4*)&out[(size_t)t * 2048 + dc] = o0;
  *(float4*)&out[(size_t)t * 2048 + dc + 4] = o1;
}

extern "C" void kernel_launch(void* const* d_in, const int* in_sizes, int n_in,
                              void* d_out, int out_size, void* d_ws, size_t ws_size,
                              hipStream_t stream) {
  const float* x  = (const float*)d_in[0];
  const float* ew = (const float*)d_in[1];
  const int* eidx = (const int*)d_in[2];
  const int* bsz  = (const int*)d_in[3];
  const float* w1 = (const float*)d_in[4];
  const float* w2 = (const float*)d_in[5];
  const float* w3 = (const float*)d_in[6];
  float* out = (float*)d_out;
  char* ws = (char*)d_ws;

  if (ws_size < WS_NEED) {
    hipMemsetAsync(d_out, 0, (size_t)out_size * 4, stream);
    return;
  }

  u16* w1T = (u16*)(ws + W1T_OFF);
  u16* w3T = (u16*)(ws + W3T_OFF);
  u16* w2T = (u16*)(ws + W2T_OFF);
  u16* xbf = (u16*)(ws + XBF_OFF);
  u16* hs  = (u16*)(ws + HS_OFF);
  u16* res = (u16*)(ws + RES_OFF);   // overlays w1T/w3T (dead after gemm1)
  int* rowtok = (int*)(ws + ROWTOK_OFF);
  int* posOf  = (int*)(ws + POS_OFF);
  int* meta   = (int*)(ws + META_OFF);

  r1_kernel<<<1, 256, 0, stream>>>(bsz, meta, rowtok);
  r2_kernel<<<64, 256, 0, stream>>>(eidx, meta, rowtok, posOf);
  convert_x_kernel<<<8192, 256, 0, stream>>>(x, xbf);
  transpose_cvt_kernel<<<dim3(32, 32, 24), 256, 0, stream>>>(w1, w2, w3, w1T, w2T, w3T);
  gemm1_kernel<<<MAXTILES * 16, 512, 0, stream>>>(xbf, w1T, w3T, rowtok, meta, hs);
  gemm2_kernel<<<MAXTILES * 8, 512, 0, stream>>>(hs, w2T, w2T, nullptr, meta, res);
  combine_kernel<<<8192, 256, 0, stream>>>(res, posOf, ew, out);
}